// Round 6
// baseline (204.776 us; speedup 1.0000x reference)
//
#include <hip/hip_runtime.h>

#define NN 128
#define NEGF -1e30f
#define DELTA 1.5e-5f

// ---- wave64 inclusive prefix-sum via DPP (6 dependent VALU ops) ----
__device__ __forceinline__ float dpp_scan_add(float x) {
    int v;
    v = __builtin_amdgcn_update_dpp(0, __float_as_int(x), 0x111, 0xf, 0xf, true);
    x += __int_as_float(v);
    v = __builtin_amdgcn_update_dpp(0, __float_as_int(x), 0x112, 0xf, 0xf, true);
    x += __int_as_float(v);
    v = __builtin_amdgcn_update_dpp(0, __float_as_int(x), 0x114, 0xf, 0xf, true);
    x += __int_as_float(v);
    v = __builtin_amdgcn_update_dpp(0, __float_as_int(x), 0x118, 0xf, 0xf, true);
    x += __int_as_float(v);
    v = __builtin_amdgcn_update_dpp(0, __float_as_int(x), 0x142, 0xa, 0xf, true);
    x += __int_as_float(v);
    v = __builtin_amdgcn_update_dpp(0, __float_as_int(x), 0x143, 0xc, 0xf, true);
    x += __int_as_float(v);
    return x;   // lane l holds sum over lanes 0..l
}

// ---- wave64 max-scan via DPP; lane 63 holds the global max ----
__device__ __forceinline__ float dpp_scan_max(float x) {
    const int negi = __float_as_int(NEGF);
    int v;
    v = __builtin_amdgcn_update_dpp(negi, __float_as_int(x), 0x111, 0xf, 0xf, false);
    x = fmaxf(x, __int_as_float(v));
    v = __builtin_amdgcn_update_dpp(negi, __float_as_int(x), 0x112, 0xf, 0xf, false);
    x = fmaxf(x, __int_as_float(v));
    v = __builtin_amdgcn_update_dpp(negi, __float_as_int(x), 0x114, 0xf, 0xf, false);
    x = fmaxf(x, __int_as_float(v));
    v = __builtin_amdgcn_update_dpp(negi, __float_as_int(x), 0x118, 0xf, 0xf, false);
    x = fmaxf(x, __int_as_float(v));
    v = __builtin_amdgcn_update_dpp(negi, __float_as_int(x), 0x142, 0xa, 0xf, false);
    x = fmaxf(x, __int_as_float(v));
    v = __builtin_amdgcn_update_dpp(negi, __float_as_int(x), 0x143, 0xc, 0xf, false);
    x = fmaxf(x, __int_as_float(v));
    return x;
}

__device__ __forceinline__ float bcast63(float x) {
    return __int_as_float(__builtin_amdgcn_readlane(__float_as_int(x), 63));
}

// walk forward in a row's sorted list to the first still-active column
__device__ __forceinline__ void advance(const unsigned long long* __restrict__ PRrow,
                                        int& p, int& h, float& rm,
                                        unsigned long long mlo, unsigned long long mhi) {
    int q = p + 1;
    for (;;) {
        unsigned long long a = PRrow[q];
        unsigned long long b = PRrow[q + 1];
        unsigned ca = (unsigned)a;
        if ((((ca & 64u) ? mhi : mlo) >> (ca & 63u)) & 1ull) {
            p = q; h = (int)ca; rm = __int_as_float((int)(a >> 32)); return;
        }
        unsigned cb = (unsigned)b;
        if ((((cb & 64u) ? mhi : mlo) >> (cb & 63u)) & 1ull) {
            p = q + 1; h = (int)cb; rm = __int_as_float((int)(b >> 32)); return;
        }
        q += 2;
    }
}

// ---------------- K0: sigmoid + per-row descending rank-sort ----------------
// PRg[r*128 + rank] = (float_bits(sig) << 32) | col ; rank 0 = row max.
__launch_bounds__(NN)
__global__ void k_sort(const float* __restrict__ P, float* __restrict__ sigS,
                       unsigned long long* __restrict__ PRg) {
    __shared__ float row[NN];
    const int r = blockIdx.x, c = threadIdx.x;
    double pv = (double)P[r * NN + c];
    float s = (float)(1.0 / (1.0 + exp(-pv)));
    sigS[r * NN + c] = s;
    row[c] = s;
    __syncthreads();
    int rank = 0;
    for (int j = 0; j < NN; ++j) {
        float v = row[j];
        rank += (v > s) || (v == s && j < c);
    }
    PRg[r * NN + rank] = ((unsigned long long)(unsigned)__float_as_int(s) << 32) | (unsigned)c;
}

// ---------------- KA: order sampling, 1 wave/dag, 16 dags/block ------------
__launch_bounds__(1024, 4)
__global__ void k_sample(const unsigned long long* __restrict__ PRg,
                         const float* __restrict__ uniforms,
                         float* __restrict__ orderF, int D) {
    __shared__ unsigned long long PR[NN * NN + 2];   // 128KB + pad
    const int tid = threadIdx.x;
    {
        const uint4* s4 = (const uint4*)PRg;
        uint4* d4 = (uint4*)PR;
        #pragma unroll
        for (int k = 0; k < 8; ++k) d4[k * 1024 + tid] = s4[k * 1024 + tid];
    }
    __syncthreads();

    const int lane = tid & 63;
    const int dag = blockIdx.x * 16 + (tid >> 6);
    if (dag >= D) return;

    const int i0 = 2 * lane, i1 = 2 * lane + 1;
    float2 uu = *reinterpret_cast<const float2*>(&uniforms[dag * NN + i0]);

    unsigned long long mlo = ~0ull, mhi = ~0ull;

    unsigned long long en0 = PR[i0 * NN], en1 = PR[i1 * NN];
    int p0 = 0, p1 = 0;
    int h0 = (int)(unsigned)en0, h1 = (int)(unsigned)en1;
    float rm0 = __int_as_float((int)(en0 >> 32));
    float rm1 = __int_as_float((int)(en1 >> 32));
    float e0 = __expf(1.0f - rm0);   // 0 marks inactive row
    float e1 = __expf(1.0f - rm1);

    #pragma unroll 1
    for (int t = 0; t < NN; ++t) {
        float usel = (t & 1) ? uu.y : uu.x;
        float ut = __int_as_float(__builtin_amdgcn_readlane(__float_as_int(usel), t >> 1));

        float incl = dpp_scan_add(e0 + e1);
        float T = bcast63(incl);
        float thr = ut * T;
        float cum1 = incl, cum0 = incl - e1;

        bool a0 = (e0 != 0.0f), a1 = (e1 != 0.0f);
        bool c0 = a0 && (cum0 >= thr);
        bool c1 = a1 && (cum1 >= thr);
        float mg = DELTA * T;
        bool amb = (a0 && fabsf(cum0 - thr) <= mg) || (a1 && fabsf(cum1 - thr) <= mg);

        unsigned long long b0 = __ballot(c0), b1 = __ballot(c1);
        unsigned long long ba = __ballot(amb);
        int lastActive = mhi ? (127 - __clzll(mhi)) : (63 - __clzll(mlo));

        int idx;
        if (__builtin_expect(ba != 0ull, 0)) {
            // ---- slow path: bit-faithful numpy-f32 emulation ----
            float l0 = 1.0f - rm0, l1v = 1.0f - rm1;
            float lvi = fmaxf(a0 ? l0 : NEGF, a1 ? l1v : NEGF);
            float lv = bcast63(dpp_scan_max(lvi));
            float f0 = a0 ? expf(l0 - lv) : 0.0f;
            float f1 = a1 ? expf(l1v - lv) : 0.0f;
            // numpy pairwise-8 accumulator sum
            int mm = lane & 3;
            float s0 = __shfl(f0, mm), s1 = __shfl(f1, mm);
            #pragma unroll
            for (int k2 = 1; k2 < 16; ++k2) {
                s0 += __shfl(f0, mm + 4 * k2);
                s1 += __shfl(f1, mm + 4 * k2);
            }
            float A00 = __shfl(s0, 0), A01 = __shfl(s0, 1), A02 = __shfl(s0, 2), A03 = __shfl(s0, 3);
            float A10 = __shfl(s1, 0), A11 = __shfl(s1, 1), A12 = __shfl(s1, 2), A13 = __shfl(s1, 3);
            float tot = ((A00 + A10) + (A01 + A11)) + ((A02 + A12) + (A03 + A13));
            float s = 0.0f;
            int pick = -1;
            for (int j = 0; j < NN; ++j) {
                float ej = __shfl((j & 1) ? f1 : f0, j >> 1);
                float pj = ej / tot;
                s += pj;
                bool aj = (j < 64) ? ((mlo >> j) & 1ull) : ((mhi >> (j - 64)) & 1ull);
                if (pick < 0 && aj && s >= ut) pick = j;
            }
            idx = (pick >= 0) ? pick : lastActive;
        } else {
            int f0i = b0 ? 2 * (__ffsll(b0) - 1) : 999;
            int f1i = b1 ? 2 * (__ffsll(b1) - 1) + 1 : 999;
            idx = min(f0i, f1i);
            if (idx == 999) idx = lastActive;
        }

        if (lane == 0) orderF[dag * NN + t] = (float)idx;

        if (idx < 64) mlo &= ~(1ull << idx);
        else          mhi &= ~(1ull << (idx - 64));
        if (idx == i0) e0 = 0.0f;
        if (idx == i1) e1 = 0.0f;

        // per-lane head advance (parallel across lanes, no wave loop)
        if (e0 != 0.0f && h0 == idx) {
            advance(&PR[i0 * NN], p0, h0, rm0, mlo, mhi);
            e0 = __expf(1.0f - rm0);
        }
        if (e1 != 0.0f && h1 == idx) {
            advance(&PR[i1 * NN], p1, h1, rm1, mlo, mhi);
            e1 = __expf(1.0f - rm1);
        }
    }
}

// ---------------- KB: edge beliefs + unpermute, 1 block per dag ------------
// sigS gathered straight from L2 (64KB table, shared by all blocks).
__launch_bounds__(512)
__global__ void k_build(const float* __restrict__ sigS,
                        const float* __restrict__ G,
                        const float* __restrict__ orderF,
                        float* __restrict__ out0) {
    __shared__ unsigned char T8[NN * NN];   // 16KB, swizzled
    __shared__ int p[NN];
    const int d = blockIdx.x;
    const int tid = threadIdx.x;
    if (tid < NN) p[tid] = (int)orderF[d * NN + tid];
    uint4 z = make_uint4(0, 0, 0, 0);
    ((uint4*)T8)[tid] = z;
    ((uint4*)T8)[512 + tid] = z;
    __syncthreads();

    const float* G0 = G + (size_t)d * 2 * NN * NN;
    const float* G1 = G0 + NN * NN;

    // strict lower triangle (8128 elems), 4-way MLP, 512 threads
    for (int base = 0; base < 8192; base += 2048) {
        float u0[4], u1[4], sg[4];
        int rr[4], cc[4];
        bool ok[4];
        #pragma unroll
        for (int j = 0; j < 4; ++j) {
            int k = base + j * 512 + tid;
            ok[j] = (k < 8128);
            if (ok[j]) {
                float fr = sqrtf(8.0f * (float)k + 1.0f);
                int r = (int)((1.0f + fr) * 0.5f);
                if (r * (r - 1) / 2 > k) --r;
                if ((r + 1) * r / 2 <= k) ++r;
                int c = k - r * (r - 1) / 2;
                rr[j] = r; cc[j] = c;
                int idx = r * NN + c;
                u0[j] = G0[idx];
                u1[j] = G1[idx];
                sg[j] = sigS[p[r] * NN + p[c]];
            }
        }
        #pragma unroll
        for (int j = 0; j < 4; ++j) {
            if (ok[j]) {
                int prr = p[rr[j]], pcc = p[cc[j]];
                // la+g0 >= l1+g1  <=>  sg*B >= (1-sg)*A
                float A = -__logf(u0[j] + 1e-10f) + 1e-10f;
                float B = -__logf(u1[j] + 1e-10f) + 1e-10f;
                T8[pcc * NN + (prr ^ (pcc & 124))] = (sg[j] * B >= (1.0f - sg[j]) * A) ? 1 : 0;
            }
        }
    }
    __syncthreads();

    float* od = out0 + (size_t)d * NN * NN;
    #pragma unroll
    for (int k = 0; k < 8; ++k) {
        int base = k * 2048 + tid * 4;
        int i = base >> 7, j = base & 127;
        const uchar4 v = *reinterpret_cast<const uchar4*>(&T8[i * NN + (j ^ (i & 124))]);
        float4 o;
        o.x = (float)v.x; o.y = (float)v.y; o.z = (float)v.z; o.w = (float)v.w;
        *reinterpret_cast<float4*>(&od[base]) = o;
    }
}

extern "C" void kernel_launch(void* const* d_in, const int* in_sizes, int n_in,
                              void* d_out, int out_size, void* d_ws, size_t ws_size,
                              hipStream_t stream) {
    const float* P        = (const float*)d_in[0];
    const float* uniforms = (const float*)d_in[1];
    const float* G        = (const float*)d_in[2];
    const int D = in_sizes[1] / NN;

    float* out0   = (float*)d_out;
    float* orderF = out0 + (size_t)D * NN * NN;
    float* sigS   = (float*)d_ws;                                   // 64KB
    unsigned long long* PRg = (unsigned long long*)((char*)d_ws + 65536);  // 128KB

    k_sort<<<NN, NN, 0, stream>>>(P, sigS, PRg);
    k_sample<<<(D + 15) / 16, 1024, 0, stream>>>(PRg, uniforms, orderF, D);
    k_build<<<D, 512, 0, stream>>>(sigS, G, orderF, out0);
}

// Round 7
// 186.320 us; speedup vs baseline: 1.0991x; 1.0991x over previous
//
#include <hip/hip_runtime.h>

#define NN 128
#define NEGF -1e30f
#define DELTA 3e-5f

// ---- wave64 inclusive prefix-sum via DPP (6 dependent VALU ops) ----
__device__ __forceinline__ float dpp_scan_add(float x) {
    int v;
    v = __builtin_amdgcn_update_dpp(0, __float_as_int(x), 0x111, 0xf, 0xf, true);
    x += __int_as_float(v);
    v = __builtin_amdgcn_update_dpp(0, __float_as_int(x), 0x112, 0xf, 0xf, true);
    x += __int_as_float(v);
    v = __builtin_amdgcn_update_dpp(0, __float_as_int(x), 0x114, 0xf, 0xf, true);
    x += __int_as_float(v);
    v = __builtin_amdgcn_update_dpp(0, __float_as_int(x), 0x118, 0xf, 0xf, true);
    x += __int_as_float(v);
    v = __builtin_amdgcn_update_dpp(0, __float_as_int(x), 0x142, 0xa, 0xf, true);
    x += __int_as_float(v);
    v = __builtin_amdgcn_update_dpp(0, __float_as_int(x), 0x143, 0xc, 0xf, true);
    x += __int_as_float(v);
    return x;   // lane l holds sum over lanes 0..l
}

// ---- wave64 max-scan via DPP; lane 63 holds the global max ----
__device__ __forceinline__ float dpp_scan_max(float x) {
    const int negi = __float_as_int(NEGF);
    int v;
    v = __builtin_amdgcn_update_dpp(negi, __float_as_int(x), 0x111, 0xf, 0xf, false);
    x = fmaxf(x, __int_as_float(v));
    v = __builtin_amdgcn_update_dpp(negi, __float_as_int(x), 0x112, 0xf, 0xf, false);
    x = fmaxf(x, __int_as_float(v));
    v = __builtin_amdgcn_update_dpp(negi, __float_as_int(x), 0x114, 0xf, 0xf, false);
    x = fmaxf(x, __int_as_float(v));
    v = __builtin_amdgcn_update_dpp(negi, __float_as_int(x), 0x118, 0xf, 0xf, false);
    x = fmaxf(x, __int_as_float(v));
    v = __builtin_amdgcn_update_dpp(negi, __float_as_int(x), 0x142, 0xa, 0xf, false);
    x = fmaxf(x, __int_as_float(v));
    v = __builtin_amdgcn_update_dpp(negi, __float_as_int(x), 0x143, 0xc, 0xf, false);
    x = fmaxf(x, __int_as_float(v));
    return x;
}

__device__ __forceinline__ float bcast63(float x) {
    return __int_as_float(__builtin_amdgcn_readlane(__float_as_int(x), 63));
}

// advance to the first still-active column, starting from the PREFETCHED
// next entry (nx); refills nx afterwards.
__device__ __forceinline__ void advance_pf(const unsigned long long* __restrict__ base,
                                           int& p, int& h, float& rm,
                                           unsigned long long& nx,
                                           unsigned long long mlo, unsigned long long mhi) {
    unsigned long long a = nx;
    int q = p + 1;
    for (;;) {
        unsigned ca = (unsigned)a;
        if ((((ca & 64u) ? mhi : mlo) >> (ca & 63u)) & 1ull) {
            p = q; h = (int)ca; rm = __int_as_float((int)(a >> 32));
            break;
        }
        ++q;
        a = base[q];
    }
    nx = base[p + 1];
}

// ---------------- K0: sigmoid + per-row descending rank-sort ----------------
// PRg[r*128 + rank] = (float_bits(sig) << 32) | col ; rank 0 = row max.
__launch_bounds__(NN)
__global__ void k_sort(const float* __restrict__ P, float* __restrict__ sigS,
                       unsigned long long* __restrict__ PRg) {
    __shared__ float row[NN];
    const int r = blockIdx.x, c = threadIdx.x;
    double pv = (double)P[r * NN + c];
    float s = (float)(1.0 / (1.0 + exp(-pv)));
    sigS[r * NN + c] = s;
    row[c] = s;
    __syncthreads();
    int rank = 0;
    for (int j = 0; j < NN; ++j) {
        float v = row[j];
        rank += (v > s) || (v == s && j < c);
    }
    PRg[r * NN + rank] = ((unsigned long long)(unsigned)__float_as_int(s) << 32) | (unsigned)c;
}

// ---------------- KA: order sampling, 1 wave/dag, incremental scan ---------
__launch_bounds__(256)
__global__ void k_sample(const unsigned long long* __restrict__ PRg,
                         const float* __restrict__ uniforms,
                         float* __restrict__ orderF, int D) {
    __shared__ unsigned long long PR[NN * NN + 4];   // 128KB + pad
    const int tid = threadIdx.x;
    {
        const uint4* s4 = (const uint4*)PRg;
        uint4* d4 = (uint4*)PR;
        #pragma unroll
        for (int k = 0; k < 32; ++k) d4[k * 256 + tid] = s4[k * 256 + tid];
    }
    __syncthreads();

    const int lane = tid & 63;
    const int dag = blockIdx.x * 4 + (tid >> 6);
    if (dag >= D) return;

    const int i0 = 2 * lane, i1 = 2 * lane + 1;
    float2 uu = *reinterpret_cast<const float2*>(&uniforms[dag * NN + i0]);

    unsigned long long mlo = ~0ull, mhi = ~0ull;

    unsigned long long en0 = PR[i0 * NN], en1 = PR[i1 * NN];
    int p0 = 0, p1 = 0;
    int h0 = (int)(unsigned)en0, h1 = (int)(unsigned)en1;
    float rm0 = __int_as_float((int)(en0 >> 32));
    float rm1 = __int_as_float((int)(en1 >> 32));
    float e0 = __expf(1.0f - rm0);   // 0 marks inactive row
    float e1 = __expf(1.0f - rm1);
    unsigned long long nx0 = PR[i0 * NN + 1], nx1 = PR[i1 * NN + 1];
    float incl = 0.0f;

    #pragma unroll 1
    for (int t = 0; t < NN; ++t) {
        float usel = (t & 1) ? uu.y : uu.x;
        float ut = __int_as_float(__builtin_amdgcn_readlane(__float_as_int(usel), t >> 1));

        if ((t & 3) == 0) incl = dpp_scan_add(e0 + e1);   // refresh (drift bound)

        float T = bcast63(incl);
        float thr = ut * T;
        float cum1 = incl, cum0 = incl - e1;

        bool a0 = (e0 != 0.0f), a1 = (e1 != 0.0f);
        bool c0 = a0 && (cum0 >= thr);
        bool c1 = a1 && (cum1 >= thr);
        float mg = DELTA * T;
        bool amb = (a0 && fabsf(cum0 - thr) <= mg) || (a1 && fabsf(cum1 - thr) <= mg);

        unsigned long long b0 = __ballot(c0), b1 = __ballot(c1);
        unsigned long long ba = __ballot(amb);
        int lastActive = mhi ? (127 - __clzll(mhi)) : (63 - __clzll(mlo));

        int idx;
        if (__builtin_expect(ba != 0ull, 0)) {
            // ---- slow path: bit-faithful numpy-f32 emulation ----
            float l0 = 1.0f - rm0, l1v = 1.0f - rm1;
            float lvi = fmaxf(a0 ? l0 : NEGF, a1 ? l1v : NEGF);
            float lv = bcast63(dpp_scan_max(lvi));
            float f0 = a0 ? expf(l0 - lv) : 0.0f;
            float f1 = a1 ? expf(l1v - lv) : 0.0f;
            // numpy pairwise-8 accumulator sum
            int mm = lane & 3;
            float s0 = __shfl(f0, mm), s1 = __shfl(f1, mm);
            #pragma unroll
            for (int k2 = 1; k2 < 16; ++k2) {
                s0 += __shfl(f0, mm + 4 * k2);
                s1 += __shfl(f1, mm + 4 * k2);
            }
            float A00 = __shfl(s0, 0), A01 = __shfl(s0, 1), A02 = __shfl(s0, 2), A03 = __shfl(s0, 3);
            float A10 = __shfl(s1, 0), A11 = __shfl(s1, 1), A12 = __shfl(s1, 2), A13 = __shfl(s1, 3);
            float tot = ((A00 + A10) + (A01 + A11)) + ((A02 + A12) + (A03 + A13));
            float s = 0.0f;
            int pick = -1;
            for (int j = 0; j < NN; ++j) {
                float ej = __shfl((j & 1) ? f1 : f0, j >> 1);
                float pj = ej / tot;
                s += pj;
                bool aj = (j < 64) ? ((mlo >> j) & 1ull) : ((mhi >> (j - 64)) & 1ull);
                if (pick < 0 && aj && s >= ut) pick = j;
            }
            idx = (pick >= 0) ? pick : lastActive;
        } else {
            int f0i = b0 ? 2 * (__ffsll(b0) - 1) : 999;
            int f1i = b1 ? 2 * (__ffsll(b1) - 1) + 1 : 999;
            idx = min(f0i, f1i);
            if (idx == 999) idx = lastActive;
        }

        if (lane == 0) orderF[dag * NN + t] = (float)idx;

        if (idx < 64) mlo &= ~(1ull << idx);
        else          mhi &= ~(1ull << (idx - 64));

        // incremental removal: subtract removed weight from suffix of scan
        int pos = idx >> 1;
        float esel = __int_as_float(__builtin_amdgcn_readlane(
                         __float_as_int((idx & 1) ? e1 : e0), pos));
        if (idx == i0) e0 = 0.0f;
        if (idx == i1) e1 = 0.0f;
        incl -= (lane >= pos) ? esel : 0.0f;

        // head advances (prefetched; usually zero LDS reads on the chain)
        float dd = 0.0f;
        if (e0 != 0.0f && h0 == idx) {
            float old = e0;
            advance_pf(&PR[i0 * NN], p0, h0, rm0, nx0, mlo, mhi);
            e0 = __expf(1.0f - rm0);
            dd = e0 - old;
        }
        if (e1 != 0.0f && h1 == idx) {
            float old = e1;
            advance_pf(&PR[i1 * NN], p1, h1, rm1, nx1, mlo, mhi);
            e1 = __expf(1.0f - rm1);
            dd += e1 - old;
        }
        unsigned long long rr = __ballot(dd != 0.0f);
        while (rr) {
            int k = __ffsll(rr) - 1; rr &= rr - 1;
            float dk = __int_as_float(__builtin_amdgcn_readlane(__float_as_int(dd), k));
            incl += (lane >= k) ? dk : 0.0f;
        }
    }
}

// ---------------- KB: edge beliefs + unpermute, 1 block per dag ------------
// sigS gathered straight from L2 (64KB table, shared by all blocks).
__launch_bounds__(512)
__global__ void k_build(const float* __restrict__ sigS,
                        const float* __restrict__ G,
                        const float* __restrict__ orderF,
                        float* __restrict__ out0) {
    __shared__ unsigned char T8[NN * NN];   // 16KB, swizzled
    __shared__ int p[NN];
    const int d = blockIdx.x;
    const int tid = threadIdx.x;
    if (tid < NN) p[tid] = (int)orderF[d * NN + tid];
    uint4 z = make_uint4(0, 0, 0, 0);
    ((uint4*)T8)[tid] = z;
    ((uint4*)T8)[512 + tid] = z;
    __syncthreads();

    const float* G0 = G + (size_t)d * 2 * NN * NN;
    const float* G1 = G0 + NN * NN;

    // strict lower triangle (8128 elems), 4-way MLP, 512 threads
    for (int base = 0; base < 8192; base += 2048) {
        float u0[4], u1[4], sg[4];
        int rr[4], cc[4];
        bool ok[4];
        #pragma unroll
        for (int j = 0; j < 4; ++j) {
            int k = base + j * 512 + tid;
            ok[j] = (k < 8128);
            if (ok[j]) {
                float fr = sqrtf(8.0f * (float)k + 1.0f);
                int r = (int)((1.0f + fr) * 0.5f);
                if (r * (r - 1) / 2 > k) --r;
                if ((r + 1) * r / 2 <= k) ++r;
                int c = k - r * (r - 1) / 2;
                rr[j] = r; cc[j] = c;
                int idx = r * NN + c;
                u0[j] = G0[idx];
                u1[j] = G1[idx];
                sg[j] = sigS[p[r] * NN + p[c]];
            }
        }
        #pragma unroll
        for (int j = 0; j < 4; ++j) {
            if (ok[j]) {
                int prr = p[rr[j]], pcc = p[cc[j]];
                // la+g0 >= l1+g1  <=>  sg*B >= (1-sg)*A
                float A = -__logf(u0[j] + 1e-10f) + 1e-10f;
                float B = -__logf(u1[j] + 1e-10f) + 1e-10f;
                T8[pcc * NN + (prr ^ (pcc & 124))] = (sg[j] * B >= (1.0f - sg[j]) * A) ? 1 : 0;
            }
        }
    }
    __syncthreads();

    float* od = out0 + (size_t)d * NN * NN;
    #pragma unroll
    for (int k = 0; k < 8; ++k) {
        int base = k * 2048 + tid * 4;
        int i = base >> 7, j = base & 127;
        const uchar4 v = *reinterpret_cast<const uchar4*>(&T8[i * NN + (j ^ (i & 124))]);
        float4 o;
        o.x = (float)v.x; o.y = (float)v.y; o.z = (float)v.z; o.w = (float)v.w;
        *reinterpret_cast<float4*>(&od[base]) = o;
    }
}

extern "C" void kernel_launch(void* const* d_in, const int* in_sizes, int n_in,
                              void* d_out, int out_size, void* d_ws, size_t ws_size,
                              hipStream_t stream) {
    const float* P        = (const float*)d_in[0];
    const float* uniforms = (const float*)d_in[1];
    const float* G        = (const float*)d_in[2];
    const int D = in_sizes[1] / NN;

    float* out0   = (float*)d_out;
    float* orderF = out0 + (size_t)D * NN * NN;
    float* sigS   = (float*)d_ws;                                   // 64KB
    unsigned long long* PRg = (unsigned long long*)((char*)d_ws + 65536);  // 128KB

    k_sort<<<NN, NN, 0, stream>>>(P, sigS, PRg);
    k_sample<<<(D + 3) / 4, 256, 0, stream>>>(PRg, uniforms, orderF, D);
    k_build<<<D, 512, 0, stream>>>(sigS, G, orderF, out0);
}

// Round 8
// 148.094 us; speedup vs baseline: 1.3827x; 1.2581x over previous
//
#include <hip/hip_runtime.h>

#define NN 128
#define NEGF -1e30f
#define DELTA 1.5e-5f

// ---- wave64 inclusive prefix-sum via DPP (6 dependent VALU ops) ----
__device__ __forceinline__ float dpp_scan_add(float x) {
    int v;
    v = __builtin_amdgcn_update_dpp(0, __float_as_int(x), 0x111, 0xf, 0xf, true);
    x += __int_as_float(v);
    v = __builtin_amdgcn_update_dpp(0, __float_as_int(x), 0x112, 0xf, 0xf, true);
    x += __int_as_float(v);
    v = __builtin_amdgcn_update_dpp(0, __float_as_int(x), 0x114, 0xf, 0xf, true);
    x += __int_as_float(v);
    v = __builtin_amdgcn_update_dpp(0, __float_as_int(x), 0x118, 0xf, 0xf, true);
    x += __int_as_float(v);
    v = __builtin_amdgcn_update_dpp(0, __float_as_int(x), 0x142, 0xa, 0xf, true);
    x += __int_as_float(v);
    v = __builtin_amdgcn_update_dpp(0, __float_as_int(x), 0x143, 0xc, 0xf, true);
    x += __int_as_float(v);
    return x;   // lane l holds sum over lanes 0..l
}

// ---- wave64 max-scan via DPP; lane 63 holds the global max ----
__device__ __forceinline__ float dpp_scan_max(float x) {
    const int negi = __float_as_int(NEGF);
    int v;
    v = __builtin_amdgcn_update_dpp(negi, __float_as_int(x), 0x111, 0xf, 0xf, false);
    x = fmaxf(x, __int_as_float(v));
    v = __builtin_amdgcn_update_dpp(negi, __float_as_int(x), 0x112, 0xf, 0xf, false);
    x = fmaxf(x, __int_as_float(v));
    v = __builtin_amdgcn_update_dpp(negi, __float_as_int(x), 0x114, 0xf, 0xf, false);
    x = fmaxf(x, __int_as_float(v));
    v = __builtin_amdgcn_update_dpp(negi, __float_as_int(x), 0x118, 0xf, 0xf, false);
    x = fmaxf(x, __int_as_float(v));
    v = __builtin_amdgcn_update_dpp(negi, __float_as_int(x), 0x142, 0xa, 0xf, false);
    x = fmaxf(x, __int_as_float(v));
    v = __builtin_amdgcn_update_dpp(negi, __float_as_int(x), 0x143, 0xc, 0xf, false);
    x = fmaxf(x, __int_as_float(v));
    return x;
}

__device__ __forceinline__ float bcast63(float x) {
    return __int_as_float(__builtin_amdgcn_readlane(__float_as_int(x), 63));
}

// ---------------- K0: sigmoid table ----------------
__global__ void k_sig(const float* __restrict__ P, float* __restrict__ sigS) {
    int i = blockIdx.x * blockDim.x + threadIdx.x;
    if (i < NN * NN) {
        double p = (double)P[i];
        sigS[i] = (float)(1.0 / (1.0 + exp(-p)));
    }
}

// -------- fused: order sampling (R4-exact) + edge-belief build -------------
// LDS swizzle: S[r][c] lives at S[r*128 + (c ^ (r & 31))]
__launch_bounds__(256)
__global__ void k_fused(const float* __restrict__ sigS,
                        const float* __restrict__ uniforms,
                        const float* __restrict__ G,
                        float* __restrict__ out0,
                        float* __restrict__ orderF, int D) {
    __shared__ float S[NN * NN];            // 64KB swizzled sigmoid table
    __shared__ int ordS[4 * NN];            // 2KB: this block's 4 orders
    __shared__ unsigned char T8[NN * NN];   // 16KB byte tile (build phase)
    const int tid = threadIdx.x;

    // stage sigP -> LDS, vectorized; swizzle permutes within 4-aligned blocks
    for (int k = 0; k < 16; ++k) {
        int idx4 = (k * 256 + tid) * 4;
        int r = idx4 >> 7, cb = idx4 & 127;
        float4 v = *reinterpret_cast<const float4*>(&sigS[idx4]);
        int x = r & 31;
        float4 w;
        switch (x & 3) {
            case 0: w = v; break;
            case 1: w = make_float4(v.y, v.x, v.w, v.z); break;
            case 2: w = make_float4(v.z, v.w, v.x, v.y); break;
            default: w = make_float4(v.w, v.z, v.y, v.x); break;
        }
        *reinterpret_cast<float4*>(&S[r * 128 + ((cb ^ x) & ~3)]) = w;
    }
    __syncthreads();

    const int lane = tid & 63;
    const int wv = tid >> 6;
    const int dag = blockIdx.x * 4 + wv;

    if (dag < D) {
        const int i0 = 2 * lane, i1 = 2 * lane + 1;
        const int x0 = i0 & 31, x1 = i1 & 31;
        const int q0 = x0 & 3, q1 = x1 & 3;
        float2 uu = *reinterpret_cast<const float2*>(&uniforms[dag * NN + i0]);

        unsigned long long mlo = ~0ull, mhi = ~0ull;

        // initial row max + holder column
        float rm0 = NEGF, rm1 = NEGF;
        int rc0 = 0, rc1 = 0;
        for (int k = 0; k < 32; ++k) {
            int cb = 4 * ((k + lane) & 31);
            float4 a = *reinterpret_cast<const float4*>(&S[i0 * 128 + (cb ^ (x0 & ~3))]);
            float4 b = *reinterpret_cast<const float4*>(&S[i1 * 128 + (cb ^ (x1 & ~3))]);
            if (a.x > rm0) { rm0 = a.x; rc0 = cb | (0 ^ q0); }
            if (a.y > rm0) { rm0 = a.y; rc0 = cb | (1 ^ q0); }
            if (a.z > rm0) { rm0 = a.z; rc0 = cb | (2 ^ q0); }
            if (a.w > rm0) { rm0 = a.w; rc0 = cb | (3 ^ q0); }
            if (b.x > rm1) { rm1 = b.x; rc1 = cb | (0 ^ q1); }
            if (b.y > rm1) { rm1 = b.y; rc1 = cb | (1 ^ q1); }
            if (b.z > rm1) { rm1 = b.z; rc1 = cb | (2 ^ q1); }
            if (b.w > rm1) { rm1 = b.w; rc1 = cb | (3 ^ q1); }
        }

        float e0 = __expf(1.0f - rm0);   // 0 marks inactive row
        float e1 = __expf(1.0f - rm1);

        #pragma unroll 1
        for (int t = 0; t < NN; ++t) {
            float usel = (t & 1) ? uu.y : uu.x;
            float ut = __int_as_float(__builtin_amdgcn_readlane(__float_as_int(usel), t >> 1));

            float incl = dpp_scan_add(e0 + e1);
            float T = bcast63(incl);
            float thr = ut * T;
            float cum1 = incl, cum0 = incl - e1;

            bool a0 = (e0 != 0.0f), a1 = (e1 != 0.0f);
            bool c0 = a0 && (cum0 >= thr);
            bool c1 = a1 && (cum1 >= thr);
            float mg = DELTA * T;
            bool amb = (a0 && fabsf(cum0 - thr) <= mg) || (a1 && fabsf(cum1 - thr) <= mg);

            unsigned long long b0 = __ballot(c0), b1 = __ballot(c1);
            unsigned long long ba = __ballot(amb);
            int lastActive = mhi ? (127 - __clzll(mhi)) : (63 - __clzll(mlo));

            int idx;
            if (__builtin_expect(ba != 0ull, 0)) {
                // ---- slow path: bit-faithful numpy-f32 emulation ----
                float l0 = 1.0f - rm0, l1v = 1.0f - rm1;
                float lvi = fmaxf(a0 ? l0 : NEGF, a1 ? l1v : NEGF);
                float lv = bcast63(dpp_scan_max(lvi));
                float f0 = a0 ? expf(l0 - lv) : 0.0f;
                float f1 = a1 ? expf(l1v - lv) : 0.0f;
                // numpy pairwise-8 accumulator sum
                int mm = lane & 3;
                float s0 = __shfl(f0, mm), s1 = __shfl(f1, mm);
                #pragma unroll
                for (int k2 = 1; k2 < 16; ++k2) {
                    s0 += __shfl(f0, mm + 4 * k2);
                    s1 += __shfl(f1, mm + 4 * k2);
                }
                float A00 = __shfl(s0, 0), A01 = __shfl(s0, 1), A02 = __shfl(s0, 2), A03 = __shfl(s0, 3);
                float A10 = __shfl(s1, 0), A11 = __shfl(s1, 1), A12 = __shfl(s1, 2), A13 = __shfl(s1, 3);
                float tot = ((A00 + A10) + (A01 + A11)) + ((A02 + A12) + (A03 + A13));
                float s = 0.0f;
                int pick = -1;
                for (int j = 0; j < NN; ++j) {
                    float ej = __shfl((j & 1) ? f1 : f0, j >> 1);
                    float pj = ej / tot;
                    s += pj;
                    bool aj = (j < 64) ? ((mlo >> j) & 1ull) : ((mhi >> (j - 64)) & 1ull);
                    if (pick < 0 && aj && s >= ut) pick = j;
                }
                idx = (pick >= 0) ? pick : lastActive;
            } else {
                int f0i = b0 ? 2 * (__ffsll(b0) - 1) : 999;
                int f1i = b1 ? 2 * (__ffsll(b1) - 1) + 1 : 999;
                idx = min(f0i, f1i);
                if (idx == 999) idx = lastActive;
            }

            if (lane == 0) ordS[wv * NN + t] = idx;

            if (idx < 64) mlo &= ~(1ull << idx);
            else          mhi &= ~(1ull << (idx - 64));
            if (idx == i0) e0 = 0.0f;
            if (idx == i1) e1 = 0.0f;
            a0 = (e0 != 0.0f); a1 = (e1 != 0.0f);

            // rescan rows whose tracked max-holder column was removed
            unsigned long long r0 = __ballot(a0 && (rc0 == idx));
            unsigned long long r1 = __ballot(a1 && (rc1 == idx));

            while (r0) {
                int L = __ffsll(r0) - 1; r0 &= r0 - 1;
                int row = 2 * L, xm = row & 31;
                float v0 = ((mlo >> lane) & 1) ? S[row * 128 + (lane ^ xm)] : NEGF;
                float v1 = ((mhi >> lane) & 1) ? S[row * 128 + ((lane + 64) ^ xm)] : NEGF;
                float m2 = bcast63(dpp_scan_max(fmaxf(v0, v1)));
                unsigned long long h0 = __ballot(v0 == m2);
                unsigned long long h1 = __ballot(v1 == m2);
                int nc = h0 ? (__ffsll(h0) - 1) : (64 + __ffsll(h1) - 1);
                if (lane == L) { rm0 = m2; rc0 = nc; e0 = __expf(1.0f - m2); }
            }
            while (r1) {
                int L = __ffsll(r1) - 1; r1 &= r1 - 1;
                int row = 2 * L + 1, xm = row & 31;
                float v0 = ((mlo >> lane) & 1) ? S[row * 128 + (lane ^ xm)] : NEGF;
                float v1 = ((mhi >> lane) & 1) ? S[row * 128 + ((lane + 64) ^ xm)] : NEGF;
                float m2 = bcast63(dpp_scan_max(fmaxf(v0, v1)));
                unsigned long long h0 = __ballot(v0 == m2);
                unsigned long long h1 = __ballot(v1 == m2);
                int nc = h0 ? (__ffsll(h0) - 1) : (64 + __ffsll(h1) - 1);
                if (lane == L) { rm1 = m2; rc1 = nc; e1 = __expf(1.0f - m2); }
            }
        }
    }
    __syncthreads();

    // ---- write order output (coalesced) ----
    #pragma unroll
    for (int k = 0; k < 2; ++k) {
        int i = k * 256 + tid;
        int dg = blockIdx.x * 4 + (i >> 7);
        if (dg < D) orderF[(size_t)blockIdx.x * 512 + i] = (float)ordS[i];
    }

    // ---- build tail: 4 dags, one 16KB tile at a time ----
    for (int w = 0; w < 4; ++w) {
        const int d = blockIdx.x * 4 + w;
        if (d >= D) break;   // uniform per block

        uint4 z = make_uint4(0, 0, 0, 0);
        #pragma unroll
        for (int k = 0; k < 4; ++k) ((uint4*)T8)[k * 256 + tid] = z;
        __syncthreads();

        const float* G0 = G + (size_t)d * 2 * NN * NN;
        const float* G1 = G0 + NN * NN;
        const int* pw = &ordS[w * NN];

        // strict lower triangle (8128 elems), 8-way MLP, 256 threads
        for (int base = 0; base < 8192; base += 2048) {
            float u0[8], u1[8], sg[8];
            int rr8[8], cc8[8];
            bool ok[8];
            #pragma unroll
            for (int j = 0; j < 8; ++j) {
                int k = base + j * 256 + tid;
                ok[j] = (k < 8128);
                if (ok[j]) {
                    float fr = sqrtf(8.0f * (float)k + 1.0f);
                    int r = (int)((1.0f + fr) * 0.5f);
                    if (r * (r - 1) / 2 > k) --r;
                    if ((r + 1) * r / 2 <= k) ++r;
                    int c = k - r * (r - 1) / 2;
                    rr8[j] = r; cc8[j] = c;
                    int idx = r * NN + c;
                    u0[j] = G0[idx];
                    u1[j] = G1[idx];
                    int prr = pw[r], pcc = pw[c];
                    sg[j] = S[prr * 128 + (pcc ^ (prr & 31))];
                }
            }
            #pragma unroll
            for (int j = 0; j < 8; ++j) {
                if (ok[j]) {
                    int prr = pw[rr8[j]], pcc = pw[cc8[j]];
                    // la+g0 >= l1+g1  <=>  sg*B >= (1-sg)*A
                    float A = -__logf(u0[j] + 1e-10f) + 1e-10f;
                    float B = -__logf(u1[j] + 1e-10f) + 1e-10f;
                    T8[pcc * NN + (prr ^ (pcc & 124))] = (sg[j] * B >= (1.0f - sg[j]) * A) ? 1 : 0;
                }
            }
        }
        __syncthreads();

        float* od = out0 + (size_t)d * NN * NN;
        #pragma unroll
        for (int k = 0; k < 16; ++k) {
            int base = k * 1024 + tid * 4;
            int i = base >> 7, j = base & 127;
            const uchar4 v = *reinterpret_cast<const uchar4*>(&T8[i * NN + (j ^ (i & 124))]);
            float4 o;
            o.x = (float)v.x; o.y = (float)v.y; o.z = (float)v.z; o.w = (float)v.w;
            *reinterpret_cast<float4*>(&od[base]) = o;
        }
        __syncthreads();
    }
}

extern "C" void kernel_launch(void* const* d_in, const int* in_sizes, int n_in,
                              void* d_out, int out_size, void* d_ws, size_t ws_size,
                              hipStream_t stream) {
    const float* P        = (const float*)d_in[0];
    const float* uniforms = (const float*)d_in[1];
    const float* G        = (const float*)d_in[2];
    const int D = in_sizes[1] / NN;

    float* out0   = (float*)d_out;
    float* orderF = out0 + (size_t)D * NN * NN;
    float* sigS   = (float*)d_ws;   // 64KB

    k_sig<<<(NN * NN + 255) / 256, 256, 0, stream>>>(P, sigS);
    k_fused<<<(D + 3) / 4, 256, 0, stream>>>(sigS, uniforms, G, out0, orderF, D);
}